// Round 10
// baseline (225.424 us; speedup 1.0000x reference)
//
#include <hip/hip_runtime.h>

typedef __attribute__((ext_vector_type(8))) short bf16x8;
typedef __attribute__((ext_vector_type(4))) float f32x4;

// fp32 -> bf16 (round-to-nearest-even), finite inputs only
__device__ __forceinline__ unsigned short f2b(float f) {
  union { float f; unsigned u; } v; v.f = f;
  return (unsigned short)((v.u + 0x7FFFu + ((v.u >> 16) & 1u)) >> 16);
}
// cheap round-half-up (for P only; half-ULP bias cancels in softmax ratio)
__device__ __forceinline__ unsigned short f2b_fast(float f) {
  union { float f; unsigned u; } v; v.f = f;
  return (unsigned short)((v.u + 0x8000u) >> 16);
}

// Fused fp32->bf16 cast for x, W_attn, W_proj + zero-fill of Oacc/Lacc.
#define XN4   786432   // 4096*768/4
#define WAN4  442368   // 2304*768/4
#define WPN4  147456   // 768*768/4
#define CVTN  1376256  // XN4+WAN4+WPN4
#define ZN4   798720   // (3145728+49152)/4  Oacc+Lacc floats as float4
__global__ void cvt_all(const float* __restrict__ x, const float* __restrict__ Wa,
                        const float* __restrict__ Wp,
                        unsigned short* __restrict__ xb, unsigned short* __restrict__ Wab,
                        unsigned short* __restrict__ Wpb, float* __restrict__ Oacc) {
  int i = blockIdx.x * 256 + threadIdx.x;
  if (i >= CVTN) {
    int z = i - CVTN;  // < ZN4
    reinterpret_cast<float4*>(Oacc)[z] = make_float4(0.f, 0.f, 0.f, 0.f);
    return;
  }
  const float* src; unsigned short* dst; int off;
  if (i < XN4)            { src = x;  dst = xb;  off = i; }
  else if (i < XN4 + WAN4){ src = Wa; dst = Wab; off = i - XN4; }
  else                    { src = Wp; dst = Wpb; off = i - XN4 - WAN4; }
  float4 f = reinterpret_cast<const float4*>(src)[off];
  ushort4 o;
  o.x = f2b(f.x); o.y = f2b(f.y); o.z = f2b(f.z); o.w = f2b(f.w);
  reinterpret_cast<ushort4*>(dst)[off] = o;
}

// qkv = x @ W_attn^T. 128x128x64 tiles, double-buffered global_load_lds.
// V-blocks (n0>=1536) swap MFMA operands so the Vt [BH][64][T] store is
// contiguous in t.  (unchanged from R7 - passed)
__global__ __launch_bounds__(256, 2)
void gemm_qkv(const unsigned short* __restrict__ A,
              const unsigned short* __restrict__ Bm,
              unsigned short* __restrict__ qb,
              unsigned short* __restrict__ kb_,
              unsigned short* __restrict__ vt) {
  __shared__ unsigned short As[2][128 * 64];
  __shared__ unsigned short Bs[2][128 * 64];
  const int K = 768;
  int tid = threadIdx.x;
  int wave = tid >> 6, lane = tid & 63;
  int quad = lane >> 4, l16 = lane & 15;
  int m0 = blockIdx.x * 128, n0 = blockIdx.y * 128;
  int wm = (wave & 1) * 64, wn = (wave >> 1) * 64;
  bool vswap = (n0 >= 1536);

  int srow = lane >> 3;
  int scol = ((lane & 7) ^ srow) << 3;

  auto stage = [&](int k0, int buf) {
#pragma unroll
    for (int i = 0; i < 4; ++i) {
      int r = wave * 32 + i * 8;
      __builtin_amdgcn_global_load_lds(
          (const __attribute__((address_space(1))) unsigned int*)(A + (size_t)(m0 + r + srow) * K + k0 + scol),
          (__attribute__((address_space(3))) unsigned int*)(&As[buf][r * 64]), 16, 0, 0);
      __builtin_amdgcn_global_load_lds(
          (const __attribute__((address_space(1))) unsigned int*)(Bm + (size_t)(n0 + r + srow) * K + k0 + scol),
          (__attribute__((address_space(3))) unsigned int*)(&Bs[buf][r * 64]), 16, 0, 0);
    }
  };

  f32x4 acc[4][4] = {};
  stage(0, 0);
  int cur = 0;

  for (int k0 = 0; k0 < K; k0 += 64) {
    __syncthreads();
    if (k0 + 64 < K) stage(k0 + 64, cur ^ 1);
#pragma unroll
    for (int kb = 0; kb < 2; ++kb) {
      int ch = (((kb << 2) | quad) ^ (l16 & 7)) << 3;
      bf16x8 af[4], bf[4];
#pragma unroll
      for (int i = 0; i < 4; ++i)
        af[i] = *reinterpret_cast<const bf16x8*>(&As[cur][(wm + i * 16 + l16) * 64 + ch]);
#pragma unroll
      for (int j = 0; j < 4; ++j)
        bf[j] = *reinterpret_cast<const bf16x8*>(&Bs[cur][(wn + j * 16 + l16) * 64 + ch]);
      if (!vswap) {
#pragma unroll
        for (int i = 0; i < 4; ++i)
#pragma unroll
          for (int j = 0; j < 4; ++j)
            acc[i][j] = __builtin_amdgcn_mfma_f32_16x16x32_bf16(af[i], bf[j], acc[i][j], 0, 0, 0);
      } else {
#pragma unroll
        for (int i = 0; i < 4; ++i)
#pragma unroll
          for (int j = 0; j < 4; ++j)
            acc[i][j] = __builtin_amdgcn_mfma_f32_16x16x32_bf16(bf[j], af[i], acc[i][j], 0, 0, 0);
      }
    }
    cur ^= 1;
  }

  const float scale2 = 0.125f * 1.44269504089f;  // 1/sqrt(64) * log2(e), folded into Q
  if (!vswap) {
#pragma unroll
    for (int i = 0; i < 4; ++i) {
      int mbase = m0 + wm + i * 16 + quad * 4;
#pragma unroll
      for (int j = 0; j < 4; ++j) {
        int f = n0 + wn + j * 16 + l16;
        int which = f / 768;
        int f2 = f - which * 768;
        int h = f2 >> 6, d = f2 & 63;
#pragma unroll
        for (int r = 0; r < 4; ++r) {
          int m = mbase + r;
          int b = m >> 11, t = m & 2047;
          int bh = b * 12 + h;
          if (which == 0) qb[((size_t)(bh * 2048 + t)) * 64 + d] = f2b(acc[i][j][r] * scale2);
          else            kb_[((size_t)(bh * 2048 + t)) * 64 + d] = f2b(acc[i][j][r]);
        }
      }
    }
  } else {
#pragma unroll
    for (int j = 0; j < 4; ++j) {
      int fbase = n0 + wn + j * 16 + quad * 4 - 1536;
#pragma unroll
      for (int i = 0; i < 4; ++i) {
        int t_g = m0 + wm + i * 16 + l16;
        int b = t_g >> 11, t = t_g & 2047;
#pragma unroll
        for (int r = 0; r < 4; ++r) {
          int f2 = fbase + r;
          int h = f2 >> 6, d = f2 & 63;
          int bh = b * 12 + h;
          vt[((size_t)(bh * 64 + d)) * 2048 + t] = f2b(acc[i][j][r]);
        }
      }
    }
  }
}

// ---------------- Flash attention: 8 independent waves / block ----------------
// R10 bisect: R8's grid/decode/512-thread structure + R1-R7-VALIDATED math
// core: non-transposed S = mfma(Q_A, K_B), C-layout scalar P writes into
// wave-private pitch-72 LDS + lgkmcnt wait (R2-R4 pattern), V as B-operand
// from Vt (R3-R7), ones-MFMA row-sum (R4-R7), fp32 atomics (R5-R7).
// No barriers; waves fully independent.
#define AT_LDP 72

__global__ __launch_bounds__(512, 4)
void attn_part(const unsigned short* __restrict__ Qb,
               const unsigned short* __restrict__ Kb,
               const unsigned short* __restrict__ Vt,
               float* __restrict__ Oacc, float* __restrict__ Lacc) {
  __shared__ unsigned short P[8 * 16 * AT_LDP];  // 18432 B, per-wave 2304 B
  const int T = 2048, D = 64;
  int wave = threadIdx.x >> 6, lane = threadIdx.x & 63;
  int quad = lane >> 4, l16 = lane & 15;

  // block -> units: 1728 blocks = 8 xcd * 3 bh * 72; unit r in 0..575 per bh
  int blk = blockIdx.x;
  int xcd = blk & 7;
  int ix = blk >> 3;                 // 0..215
  int bh = xcd * 3 + ix / 72;
  int r = (ix % 72) * 8 + wave;      // 0..575
  int qt = 0, c = 0;
#pragma unroll
  for (int G = 0; G < 8; ++G) {
    int cnt = 16 * (G + 1);
    if (r >= cnt) { r -= cnt; }
    else { qt = G * 16 + r / (G + 1); c = r % (G + 1); break; }
  }
  int qrow = qt * 16;
  int kbeg = c * 256;
  int kend = kbeg + 256; if (kend > qrow + 16) kend = qrow + 16;

  const unsigned short* Qp = Qb + (size_t)bh * T * D;
  const unsigned short* Kp = Kb + (size_t)bh * T * D;
  const unsigned short* Vp = Vt + (size_t)bh * D * T;
  unsigned short* Pw = P + wave * 16 * AT_LDP;

  // Q as A-operand: A[m=l16 -> q][k=quad*8+j]; Qb pre-scaled by log2e/8
  bf16x8 aq[2];
#pragma unroll
  for (int cc = 0; cc < 2; ++cc)
    aq[cc] = *reinterpret_cast<const bf16x8*>(Qp + (qrow + l16) * D + cc * 32 + quad * 8);

  bf16x8 ones;
#pragma unroll
  for (int e = 0; e < 8; ++e) ones[e] = (short)0x3F80;  // bf16 1.0

  f32x4 o[4] = {};
  f32x4 lacc = {};

  for (int k0 = kbeg; k0 < kend; k0 += 64) {
    // K frags as B-operand (n = l16 -> key), direct from global (R1-R7 form)
    bf16x8 kf[4][2];
#pragma unroll
    for (int nt = 0; nt < 4; ++nt) {
      const unsigned short* kr = Kp + (size_t)(k0 + nt * 16 + l16) * D + quad * 8;
      kf[nt][0] = *reinterpret_cast<const bf16x8*>(kr);
      kf[nt][1] = *reinterpret_cast<const bf16x8*>(kr + 32);
    }
    // S = Q K^T (non-transposed, R1-R7 validated): C col=l16->key, row=quad*4+rr->q
    f32x4 sacc[4] = {};
#pragma unroll
    for (int nt = 0; nt < 4; ++nt) {
      sacc[nt] = __builtin_amdgcn_mfma_f32_16x16x32_bf16(aq[0], kf[nt][0], sacc[nt], 0, 0, 0);
      sacc[nt] = __builtin_amdgcn_mfma_f32_16x16x32_bf16(aq[1], kf[nt][1], sacc[nt], 0, 0, 0);
    }
    // V frags as B-operand from Vt (R3-R7 validated), issued before softmax
    bf16x8 vf[4][2];
#pragma unroll
    for (int dt = 0; dt < 4; ++dt) {
      const unsigned short* vr = Vp + (size_t)(dt * 16 + l16) * T + k0 + quad * 8;
      vf[dt][0] = *reinterpret_cast<const bf16x8*>(vr);
      vf[dt][1] = *reinterpret_cast<const bf16x8*>(vr + 32);
    }

    // mask + exp2 (no-max softmax, m=0; R4-R7 validated)
#pragma unroll
    for (int nt = 0; nt < 4; ++nt) {
      int col = k0 + nt * 16 + l16;
#pragma unroll
      for (int rr = 0; rr < 4; ++rr) {
        int row = qrow + quad * 4 + rr;
        float s = (col <= row) ? sacc[nt][rr] : -1e30f;
        sacc[nt][rr] = exp2f(s);
      }
    }

    // P: C-layout -> wave-private LDS (pitch 72, R2-R4 validated pattern)
#pragma unroll
    for (int nt = 0; nt < 4; ++nt)
#pragma unroll
      for (int rr = 0; rr < 4; ++rr)
        Pw[(quad * 4 + rr) * AT_LDP + nt * 16 + l16] = f2b_fast(sacc[nt][rr]);
    __asm__ volatile("s_waitcnt lgkmcnt(0)" ::: "memory");

    // O += P V ; l += P * ones (R4-R7 validated)
    bf16x8 ap0 = *reinterpret_cast<const bf16x8*>(Pw + l16 * AT_LDP + quad * 8);
    bf16x8 ap1 = *reinterpret_cast<const bf16x8*>(Pw + l16 * AT_LDP + 32 + quad * 8);
#pragma unroll
    for (int dt = 0; dt < 4; ++dt) {
      o[dt] = __builtin_amdgcn_mfma_f32_16x16x32_bf16(ap0, vf[dt][0], o[dt], 0, 0, 0);
      o[dt] = __builtin_amdgcn_mfma_f32_16x16x32_bf16(ap1, vf[dt][1], o[dt], 0, 0, 0);
    }
    lacc = __builtin_amdgcn_mfma_f32_16x16x32_bf16(ap0, ones, lacc, 0, 0, 0);
    lacc = __builtin_amdgcn_mfma_f32_16x16x32_bf16(ap1, ones, lacc, 0, 0, 0);
    __asm__ volatile("" ::: "memory");  // this iter's P reads before next iter's writes
  }

  // O partials: C-layout row = q (quad*4+rr), col = d (dt*16+l16)
#pragma unroll
  for (int dt = 0; dt < 4; ++dt)
#pragma unroll
    for (int rr = 0; rr < 4; ++rr) {
      int row = qrow + quad * 4 + rr;
      atomicAdd(&Oacc[((size_t)(bh * T + row)) * 64 + dt * 16 + l16], o[dt][rr]);
    }
  // L: lacc C-layout row = q, all cols equal; write from l16==0 (R5-R7 form)
  if (l16 == 0) {
#pragma unroll
    for (int rr = 0; rr < 4; ++rr)
      atomicAdd(&Lacc[bh * T + qrow + quad * 4 + rr], lacc[rr]);
  }
}

// out = normalize(Oacc/Lacc) @ W_proj^T, fp32 out. 64x128x64 tiles, fully
// pipelined (B dbuf DMA; A loads one tile ahead; fused normalization).
// (unchanged from R7 - passed)
__global__ __launch_bounds__(256, 2)
void gemm_proj(const float* __restrict__ Oacc, const float* __restrict__ Lacc,
               const unsigned short* __restrict__ Wpb, float* __restrict__ out) {
  __shared__ unsigned short As[2][64 * 64];
  __shared__ unsigned short Bs[2][128 * 64];
  int tid = threadIdx.x;
  int wave = tid >> 6, lane = tid & 63;
  int quad = lane >> 4, l16 = lane & 15;
  int m0 = blockIdx.x * 64, n0 = blockIdx.y * 128;
  int wm = (wave & 1) * 32, wn = (wave >> 1) * 64;

  int srow = lane >> 3;
  int scol = ((lane & 7) ^ srow) << 3;

  int arow = tid >> 2;
  int acg = (tid & 3) * 2;
  int t_g = m0 + arow;
  int bb = t_g >> 11, tt = t_g & 2047;
  int asw = arow & 7;

  auto stageB = [&](int k0, int buf) {
#pragma unroll
    for (int i = 0; i < 4; ++i) {
      int r = wave * 32 + i * 8;
      __builtin_amdgcn_global_load_lds(
          (const __attribute__((address_space(1))) unsigned int*)(Wpb + (size_t)(n0 + r + srow) * 768 + k0 + scol),
          (__attribute__((address_space(3))) unsigned int*)(&Bs[buf][r * 64]), 16, 0, 0);
    }
  };
  auto loadA = [&](int k0, float4* a, float& rl) {
    int h = k0 >> 6;
    const float* arp = Oacc + ((size_t)((bb * 12 + h) * 2048 + tt)) * 64 + acg * 8;
    rl = 1.0f / Lacc[(bb * 12 + h) * 2048 + tt];
    a[0] = reinterpret_cast<const float4*>(arp)[0];
    a[1] = reinterpret_cast<const float4*>(arp)[1];
    a[2] = reinterpret_cast<const float4*>(arp)[2];
    a[3] = reinterpret_cast<const float4*>(arp)[3];
  };
  auto writeA = [&](const float4* a, float rl, int buf) {
    bf16x8 p0, p1;
    p0[0] = (short)f2b(a[0].x * rl); p0[1] = (short)f2b(a[0].y * rl);
    p0[2] = (short)f2b(a[0].z * rl); p0[3] = (short)f2b(a[0].w * rl);
    p0[4] = (short)f2b(a[1].x * rl); p0[5] = (short)f2b(a[1].y * rl);
    p0[6] = (short)f2b(a[1].z * rl); p0[7] = (short)f2b(a[1].w * rl);
    p1[0] = (short)f2b(a[2].x * rl); p1[1] = (short)f2b(a[2].y * rl);
    p1[2] = (short)f2b(a[2].z * rl); p1[3] = (short)f2b(a[2].w * rl);
    p1[4] = (short)f2b(a[3].x * rl); p1[5] = (short)f2b(a[3].y * rl);
    p1[6] = (short)f2b(a[3].z * rl); p1[7] = (short)f2b(a[3].w * rl);
    *reinterpret_cast<bf16x8*>(&As[buf][arow * 64 + ((acg ^ asw) << 3)]) = p0;
    *reinterpret_cast<bf16x8*>(&As[buf][arow * 64 + (((acg + 1) ^ asw) << 3)]) = p1;
  };

  f32x4 acc[2][4] = {};

  float4 aP[4], aN[4];
  float rlP, rlN;
  stageB(0, 0);
  loadA(0, aP, rlP);
  loadA(64, aN, rlN);
  writeA(aP, rlP, 0);
  int cur = 0;

  for (int k0 = 0; k0 < 768; k0 += 64) {
    __syncthreads();
    if (k0 + 64 < 768) {
      stageB(k0 + 64, cur ^ 1);
      writeA(aN, rlN, cur ^ 1);
      if (k0 + 128 < 768) loadA(k0 + 128, aN, rlN);
    }
#pragma unroll
    for (int kb = 0; kb < 2; ++kb) {
      int ch = (((kb << 2) | quad) ^ (l16 & 7)) << 3;
      bf16x8 af[2], bf[4];
#pragma unroll
      for (int i = 0; i < 2; ++i)
        af[i] = *reinterpret_cast<const bf16x8*>(&As[cur][(wm + i * 16 + l16) * 64 + ch]);
#pragma unroll
      for (int j = 0; j < 4; ++j)
        bf[j] = *reinterpret_cast<const bf16x8*>(&Bs[cur][(wn + j * 16 + l16) * 64 + ch]);
#pragma unroll
      for (int i = 0; i < 2; ++i)
#pragma unroll
        for (int j = 0; j < 4; ++j)
          acc[i][j] = __builtin_amdgcn_mfma_f32_16x16x32_bf16(af[i], bf[j], acc[i][j], 0, 0, 0);
    }
    cur ^= 1;
  }

#pragma unroll
  for (int i = 0; i < 2; ++i) {
    int mbase = m0 + wm + i * 16 + quad * 4;
#pragma unroll
    for (int j = 0; j < 4; ++j) {
      int col = n0 + wn + j * 16 + l16;
#pragma unroll
      for (int r = 0; r < 4; ++r)
        out[(size_t)(mbase + r) * 768 + col] = acc[i][j][r];
    }
  }
}

extern "C" void kernel_launch(void* const* d_in, const int* in_sizes, int n_in,
                              void* d_out, int out_size, void* d_ws, size_t ws_size,
                              hipStream_t stream) {
  const float* x  = (const float*)d_in[0];   // [2,2048,768]
  const float* Wa = (const float*)d_in[1];   // [2304,768]
  const float* Wp = (const float*)d_in[2];   // [768,768]
  float* out = (float*)d_out;                // [2,2048,768] fp32

  unsigned short* ws = (unsigned short*)d_ws;
  unsigned short* xb  = ws;                  // 4096*768
  unsigned short* Wab = xb  + 3145728;       // 2304*768
  unsigned short* Wpb = Wab + 1769472;       // 768*768
  unsigned short* Qb  = Wpb + 589824;        // 24*2048*64 (pre-scaled)
  unsigned short* Kb  = Qb  + 3145728;
  unsigned short* Vt  = Kb  + 3145728;       // [24][64][2048]
  float*          Oacc = (float*)(Vt + 3145728);  // 24*2048*64 fp32
  float*          Lacc = Oacc + 3145728;          // 24*2048 fp32 (contiguous)

  cvt_all<<<(CVTN + ZN4) / 256, 256, 0, stream>>>(x, Wa, Wp, xb, Wab, Wpb, Oacc);

  gemm_qkv<<<dim3(32, 18), 256, 0, stream>>>(xb, Wab, Qb, Kb, Vt);

  attn_part<<<1728, 512, 0, stream>>>(Qb, Kb, Vt, Oacc, Lacc);

  gemm_proj<<<dim3(64, 6), 256, 0, stream>>>(Oacc, Lacc, Wpb, out);
}